// Round 1
// baseline (203.966 us; speedup 1.0000x reference)
//
#include <hip/hip_runtime.h>
#include <math.h>

// Problem constants
#define TT 512
#define CC 1024
#define NH 16
#define NKV 8
#define HD 64
static constexpr float EPS_ = 1e-6f;

// ---------------------------------------------------------------------------
// fp32 GEMM tile: C[64x64] += A[64xK] @ W[Kx64], K=1024, lda=1024.
// 256 threads, BK=32, A staged transposed (pad 68 keeps 16B align + staggers banks).
// ---------------------------------------------------------------------------
__device__ __forceinline__ void gemm_tile(
    const float* __restrict__ A, const float* __restrict__ W,
    float* __restrict__ Cp, int ldW, int cb, int row0)
{
  __shared__ __align__(16) float At[32][68];
  __shared__ __align__(16) float Bt[32][68];
  const int tid = threadIdx.x;
  const int tr = tid >> 4, tc = tid & 15;
  float acc[4][4] = {};

  for (int k0 = 0; k0 < 1024; k0 += 32) {
    __syncthreads();
    // stage A (64 rows x 32 k), transposed into At[k][r]
#pragma unroll
    for (int e = 0; e < 2; ++e) {
      int idx = tid + e * 256;          // 0..511
      int r = idx >> 3, c4 = idx & 7;
      const float4 a4 = *reinterpret_cast<const float4*>(&A[(row0 + r) * 1024 + k0 + c4 * 4]);
      At[c4 * 4 + 0][r] = a4.x; At[c4 * 4 + 1][r] = a4.y;
      At[c4 * 4 + 2][r] = a4.z; At[c4 * 4 + 3][r] = a4.w;
    }
    // stage B (32 k x 64 cols)
#pragma unroll
    for (int e = 0; e < 2; ++e) {
      int idx = tid + e * 256;
      int r = idx >> 4, c4 = idx & 15;
      const float4 b4 = *reinterpret_cast<const float4*>(&W[(k0 + r) * ldW + cb + c4 * 4]);
      *reinterpret_cast<float4*>(&Bt[r][c4 * 4]) = b4;
    }
    __syncthreads();
#pragma unroll 8
    for (int kk = 0; kk < 32; ++kk) {
      float4 a = *reinterpret_cast<const float4*>(&At[kk][tr * 4]);
      float4 b = *reinterpret_cast<const float4*>(&Bt[kk][tc * 4]);
      float av[4] = {a.x, a.y, a.z, a.w};
      float bv[4] = {b.x, b.y, b.z, b.w};
#pragma unroll
      for (int i = 0; i < 4; ++i)
#pragma unroll
        for (int j = 0; j < 4; ++j)
          acc[i][j] = fmaf(av[i], bv[j], acc[i][j]);
    }
  }
#pragma unroll
  for (int i = 0; i < 4; ++i) {
    float4 o = make_float4(acc[i][0], acc[i][1], acc[i][2], acc[i][3]);
    *reinterpret_cast<float4*>(&Cp[(row0 + tr * 4 + i) * ldW + cb + tc * 4]) = o;
  }
}

// grid (32, 8): bx<16 -> Wq, bx<24 -> Wk, else Wv
__global__ __launch_bounds__(256) void qkv_gemm_kernel(
    const float* __restrict__ x,
    const float* __restrict__ Wq, const float* __restrict__ Wk, const float* __restrict__ Wv,
    float* __restrict__ qb, float* __restrict__ kb, float* __restrict__ vb)
{
  int bx = blockIdx.x, by = blockIdx.y;
  const float* W; float* Cp; int ldW, cb;
  if (bx < 16)      { W = Wq; Cp = qb; ldW = 1024; cb = bx * 64; }
  else if (bx < 24) { W = Wk; Cp = kb; ldW = 512;  cb = (bx - 16) * 64; }
  else              { W = Wv; Cp = vb; ldW = 512;  cb = (bx - 24) * 64; }
  gemm_tile(x, W, Cp, ldW, cb, by * 64);
}

// grid (16, 8)
__global__ __launch_bounds__(256) void out_gemm_kernel(
    const float* __restrict__ y, const float* __restrict__ Wo, float* __restrict__ out)
{
  gemm_tile(y, Wo, out, 1024, blockIdx.x * 64, blockIdx.y * 64);
}

// ---------------------------------------------------------------------------
// RoPE + RMS-norm, in place. One 64-lane wave per (t, head) row.
// Rows [0, 8192): q rows; rows [8192, 12288): k rows.
// ---------------------------------------------------------------------------
__global__ __launch_bounds__(256) void rope_rms_kernel(
    float* __restrict__ qb, float* __restrict__ kb,
    const float* __restrict__ cosb, const float* __restrict__ sinb)
{
  int rid = blockIdx.x * 4 + (threadIdx.x >> 6);
  int lane = threadIdx.x & 63;
  float* p; int t;
  if (rid < TT * NH) { t = rid >> 4; p = qb + t * 1024 + (rid & 15) * 64; }
  else { int r2 = rid - TT * NH; t = r2 >> 3; p = kb + t * 512 + (r2 & 7) * 64; }

  float v = p[lane];
  float part = __shfl_xor(v, 32);
  int f = lane & 31;
  float c = cosb[t * 32 + f], s = sinb[t * 32 + f];
  // lane<32: x1*c - x2*s ; lane>=32: x1*s + x2*c  (x1=part/v per half)
  float o = (lane < 32) ? (v * c - part * s) : (part * s + v * c);
  float ss = o * o;
#pragma unroll
  for (int off = 32; off; off >>= 1) ss += __shfl_xor(ss, off);
  float r = rsqrtf(ss * (1.0f / 64.0f) + EPS_);
  p[lane] = o * r;
}

// ---------------------------------------------------------------------------
// Tropical causal attention. Block = (4 q-rows, one head), 256 thr (4 waves,
// 1 wave per q-row). K tile staged transposed kT[d][j] (pad 65, conflict-free),
// V tile vS[j][d]. Online softmax over j-tiles of 64.
// scores[i][j] = max_d(q[i][d] + k[j][d]); causal mask j<=i.
// ---------------------------------------------------------------------------
__global__ __launch_bounds__(256) void attn_kernel(
    const float* __restrict__ qb, const float* __restrict__ kb,
    const float* __restrict__ vb, float* __restrict__ yb)
{
  __shared__ float kT[64][65];
  __shared__ float vS[64][65];
  __shared__ __align__(16) float qS[4][64];
  __shared__ __align__(16) float pS[4][64];

  const int tid = threadIdx.x;
  const int w = tid >> 6, lane = tid & 63;
  const int h = blockIdx.y, g = h >> 1;
  const int i0 = blockIdx.x * 4;
  const int i = i0 + w;

  // stage the 4 q rows for this block
  qS[w][lane] = qb[i * 1024 + h * 64 + lane];

  float acc = 0.f, l = 0.f, m = -INFINITY;
  const int jt_max = i0 >> 6;   // 4-row group never straddles a 64 boundary

  for (int jt = 0; jt <= jt_max; ++jt) {
    const int j0 = jt * 64;
    __syncthreads();
    // stage K (transposed) and V tiles for kv head g
    {
      int c4 = tid & 15, r0 = tid >> 4;   // r0 in 0..15
#pragma unroll
      for (int rr = 0; rr < 4; ++rr) {
        int r = r0 + rr * 16;
        float4 kv = *reinterpret_cast<const float4*>(&kb[(j0 + r) * 512 + g * 64 + c4 * 4]);
        kT[c4 * 4 + 0][r] = kv.x; kT[c4 * 4 + 1][r] = kv.y;
        kT[c4 * 4 + 2][r] = kv.z; kT[c4 * 4 + 3][r] = kv.w;
        float4 vv = *reinterpret_cast<const float4*>(&vb[(j0 + r) * 512 + g * 64 + c4 * 4]);
        vS[r][c4 * 4 + 0] = vv.x; vS[r][c4 * 4 + 1] = vv.y;
        vS[r][c4 * 4 + 2] = vv.z; vS[r][c4 * 4 + 3] = vv.w;
      }
    }
    __syncthreads();

    // ---- score phase: lane = j ----
    float s = -INFINITY;
    const float4* q4 = reinterpret_cast<const float4*>(qS[w]);
#pragma unroll
    for (int d4 = 0; d4 < 16; ++d4) {
      float4 qv = q4[d4];
      s = fmaxf(s, qv.x + kT[d4 * 4 + 0][lane]);
      s = fmaxf(s, qv.y + kT[d4 * 4 + 1][lane]);
      s = fmaxf(s, qv.z + kT[d4 * 4 + 2][lane]);
      s = fmaxf(s, qv.w + kT[d4 * 4 + 3][lane]);
    }
    if (j0 + lane > i) s = -INFINITY;

    // online softmax update
    float mt = s;
#pragma unroll
    for (int off = 32; off; off >>= 1) mt = fmaxf(mt, __shfl_xor(mt, off));
    float mnew = fmaxf(m, mt);              // finite from tile 0 onward
    float scale = __expf(m - mnew);         // first tile: exp(-inf)=0, harmless
    float pp = __expf(s - mnew);            // masked lanes: exp(-inf)=0
    float psum = pp;
#pragma unroll
    for (int off = 32; off; off >>= 1) psum += __shfl_xor(psum, off);
    l = l * scale + psum;
    acc *= scale;
    m = mnew;
    pS[w][lane] = pp;
    __syncthreads();   // uniform across block (same jt count for all waves)

    // ---- PV phase: lane = d ----
    const float4* p4 = reinterpret_cast<const float4*>(pS[w]);
#pragma unroll
    for (int j4 = 0; j4 < 16; ++j4) {
      float4 pv = p4[j4];
      acc = fmaf(pv.x, vS[j4 * 4 + 0][lane], acc);
      acc = fmaf(pv.y, vS[j4 * 4 + 1][lane], acc);
      acc = fmaf(pv.z, vS[j4 * 4 + 2][lane], acc);
      acc = fmaf(pv.w, vS[j4 * 4 + 3][lane], acc);
    }
  }

  yb[i * 1024 + h * 64 + lane] = acc / l;
}

// ---------------------------------------------------------------------------
extern "C" void kernel_launch(void* const* d_in, const int* in_sizes, int n_in,
                              void* d_out, int out_size, void* d_ws, size_t ws_size,
                              hipStream_t stream) {
  const float* x    = (const float*)d_in[0];
  const float* cosb = (const float*)d_in[1];
  const float* sinb = (const float*)d_in[2];
  const float* Wq   = (const float*)d_in[3];
  const float* Wk   = (const float*)d_in[4];
  const float* Wv   = (const float*)d_in[5];
  const float* Wo   = (const float*)d_in[6];
  float* out = (float*)d_out;

  float* ws = (float*)d_ws;
  float* qbuf = ws;                       // 512 x 1024
  float* kbuf = qbuf + TT * CC;           // 512 x 512
  float* vbuf = kbuf + TT * 512;          // 512 x 512
  float* ybuf = vbuf + TT * 512;          // 512 x 1024

  qkv_gemm_kernel<<<dim3(32, 8), 256, 0, stream>>>(x, Wq, Wk, Wv, qbuf, kbuf, vbuf);
  rope_rms_kernel<<<dim3((TT * NH + TT * NKV) / 4), 256, 0, stream>>>(qbuf, kbuf, cosb, sinb);
  attn_kernel<<<dim3(TT / 4, NH), 256, 0, stream>>>(qbuf, kbuf, vbuf, ybuf);
  out_gemm_kernel<<<dim3(16, 8), 256, 0, stream>>>(ybuf, Wo, out);
}

// Round 2
// 94.637 us; speedup vs baseline: 2.1552x; 2.1552x over previous
//
#include <hip/hip_runtime.h>
#include <hip/hip_bf16.h>
#include <math.h>

#define TT 512
#define CC 1024
#define NH 16
#define NKV 8
#define HD 64
static constexpr float EPS_ = 1e-6f;

typedef short bf16x8 __attribute__((ext_vector_type(8)));
typedef float f32x4 __attribute__((ext_vector_type(4)));

__device__ __forceinline__ ushort f2bf(float f) {
  union { __hip_bfloat16 h; ushort u; } cv;
  cv.h = __float2bfloat16(f);
  return cv.u;
}

// ---------------------------------------------------------------------------
// prep: x -> bf16 (same layout); Wq/Wk/Wv/Wo -> transposed bf16 Wt[n][k]
// grid.x = 256 (x convert) + 768 (64x64 transpose tiles)
// ---------------------------------------------------------------------------
__global__ __launch_bounds__(256) void prep_kernel(
    const float* __restrict__ x,
    const float* __restrict__ Wq, const float* __restrict__ Wk,
    const float* __restrict__ Wv, const float* __restrict__ Wo,
    ushort* __restrict__ xb, ushort* __restrict__ Wtq, ushort* __restrict__ Wtk,
    ushort* __restrict__ Wtv, ushort* __restrict__ Wto)
{
  int b = blockIdx.x;
  if (b < 256) {
    int base = b * 2048 + threadIdx.x * 8;
    float4 f0 = *reinterpret_cast<const float4*>(&x[base]);
    float4 f1 = *reinterpret_cast<const float4*>(&x[base + 4]);
    union { ushort u[8]; uint4 v; } pk;
    pk.u[0] = f2bf(f0.x); pk.u[1] = f2bf(f0.y); pk.u[2] = f2bf(f0.z); pk.u[3] = f2bf(f0.w);
    pk.u[4] = f2bf(f1.x); pk.u[5] = f2bf(f1.y); pk.u[6] = f2bf(f1.z); pk.u[7] = f2bf(f1.w);
    *reinterpret_cast<uint4*>(&xb[base]) = pk.v;
    return;
  }
  b -= 256;
  const float* W; ushort* Wt; int ldW, tr, tc;
  if (b < 256)      { W = Wq; Wt = Wtq; ldW = 1024; tr = b >> 4;       tc = b & 15; }
  else if (b < 384) { int q = b - 256; W = Wk; Wt = Wtk; ldW = 512; tr = q >> 3; tc = q & 7; }
  else if (b < 512) { int q = b - 384; W = Wv; Wt = Wtv; ldW = 512; tr = q >> 3; tc = q & 7; }
  else              { int q = b - 512; W = Wo; Wt = Wto; ldW = 1024; tr = q >> 4; tc = q & 15; }
  const int k0 = tr * 64, n0 = tc * 64;
  __shared__ float ft[64][65];
  const int t = threadIdx.x;
#pragma unroll
  for (int it = 0; it < 4; ++it) {
    int q = t + it * 256;           // 0..1023
    int r = q >> 4, c4 = q & 15;
    float4 f = *reinterpret_cast<const float4*>(&W[(k0 + r) * ldW + n0 + c4 * 4]);
    ft[r][c4 * 4 + 0] = f.x; ft[r][c4 * 4 + 1] = f.y;
    ft[r][c4 * 4 + 2] = f.z; ft[r][c4 * 4 + 3] = f.w;
  }
  __syncthreads();
#pragma unroll
  for (int it = 0; it < 2; ++it) {
    int q = t + it * 256;           // 0..511
    int n = q >> 3, kc = q & 7;
    union { ushort u[8]; uint4 v; } pk;
#pragma unroll
    for (int j = 0; j < 8; ++j) pk.u[j] = f2bf(ft[kc * 8 + j][n]);
    *reinterpret_cast<uint4*>(&Wt[(n0 + n) * 1024 + k0 + kc * 8]) = pk.v;
  }
}

// ---------------------------------------------------------------------------
// bf16 MFMA GEMM: C[64x64 tile] = A[M][1024] @ Bt[N][1024]^T, fp32 out.
// 256 thr = 4 waves in 2x2; each wave 32x32 via 2x2 fragments of 16x16x32.
// ---------------------------------------------------------------------------
__device__ __forceinline__ void mfma_gemm64(
    const ushort* __restrict__ A, const ushort* __restrict__ Bt,
    float* __restrict__ C, int ldC, int row0, int col0)
{
  __shared__ ushort At[64][72];
  __shared__ ushort Bs[64][72];
  const int tid = threadIdx.x;
  const int lane = tid & 63, w = tid >> 6;
  const int m0 = (w & 1) * 32, n0 = (w >> 1) * 32;
  const int lr = lane & 15, lk = (lane >> 4) * 8;
  f32x4 acc[2][2] = {};
  const int sr = tid >> 2;             // staging row 0..63
  const int sc = (tid & 3) * 16;       // staging k offset (elems)
  const ushort* Ap = &A[(row0 + sr) * 1024 + sc];
  const ushort* Bp = &Bt[(col0 + sr) * 1024 + sc];

  for (int k0 = 0; k0 < 1024; k0 += 64) {
    __syncthreads();
    uint4 a0 = *reinterpret_cast<const uint4*>(Ap + k0);
    uint4 a1 = *reinterpret_cast<const uint4*>(Ap + k0 + 8);
    uint4 b0 = *reinterpret_cast<const uint4*>(Bp + k0);
    uint4 b1 = *reinterpret_cast<const uint4*>(Bp + k0 + 8);
    *reinterpret_cast<uint4*>(&At[sr][sc]) = a0;
    *reinterpret_cast<uint4*>(&At[sr][sc + 8]) = a1;
    *reinterpret_cast<uint4*>(&Bs[sr][sc]) = b0;
    *reinterpret_cast<uint4*>(&Bs[sr][sc + 8]) = b1;
    __syncthreads();
#pragma unroll
    for (int kk = 0; kk < 2; ++kk) {
      bf16x8 af[2], bg[2];
      af[0] = *reinterpret_cast<const bf16x8*>(&At[m0 + lr][kk * 32 + lk]);
      af[1] = *reinterpret_cast<const bf16x8*>(&At[m0 + 16 + lr][kk * 32 + lk]);
      bg[0] = *reinterpret_cast<const bf16x8*>(&Bs[n0 + lr][kk * 32 + lk]);
      bg[1] = *reinterpret_cast<const bf16x8*>(&Bs[n0 + 16 + lr][kk * 32 + lk]);
#pragma unroll
      for (int mi = 0; mi < 2; ++mi)
#pragma unroll
        for (int ni = 0; ni < 2; ++ni)
          acc[mi][ni] = __builtin_amdgcn_mfma_f32_16x16x32_bf16(af[mi], bg[ni], acc[mi][ni], 0, 0, 0);
    }
  }
  const int crow = (lane >> 4) * 4, ccol = lane & 15;
#pragma unroll
  for (int mi = 0; mi < 2; ++mi)
#pragma unroll
    for (int ni = 0; ni < 2; ++ni) {
      int rb = row0 + m0 + mi * 16 + crow;
      int cc = col0 + n0 + ni * 16 + ccol;
#pragma unroll
      for (int r = 0; r < 4; ++r)
        C[(rb + r) * ldC + cc] = acc[mi][ni][r];
    }
}

__global__ __launch_bounds__(256) void qkv_mfma_kernel(
    const ushort* __restrict__ xb,
    const ushort* __restrict__ Wtq, const ushort* __restrict__ Wtk, const ushort* __restrict__ Wtv,
    float* __restrict__ qb, float* __restrict__ kb, float* __restrict__ vb)
{
  int bx = blockIdx.x, by = blockIdx.y;
  if (bx < 16)      mfma_gemm64(xb, Wtq, qb, 1024, by * 64, bx * 64);
  else if (bx < 24) mfma_gemm64(xb, Wtk, kb, 512, by * 64, (bx - 16) * 64);
  else              mfma_gemm64(xb, Wtv, vb, 512, by * 64, (bx - 24) * 64);
}

__global__ __launch_bounds__(256) void out_mfma_kernel(
    const ushort* __restrict__ yb, const ushort* __restrict__ Wto, float* __restrict__ out)
{
  mfma_gemm64(yb, Wto, out, 1024, blockIdx.y * 64, blockIdx.x * 64);
}

// ---------------------------------------------------------------------------
// RoPE + RMS-norm, in place (fp32). One 64-lane wave per (t, head) row.
// ---------------------------------------------------------------------------
__global__ __launch_bounds__(256) void rope_rms_kernel(
    float* __restrict__ qb, float* __restrict__ kb,
    const float* __restrict__ cosb, const float* __restrict__ sinb)
{
  int rid = blockIdx.x * 4 + (threadIdx.x >> 6);
  int lane = threadIdx.x & 63;
  float* p; int t;
  if (rid < TT * NH) { t = rid >> 4; p = qb + t * 1024 + (rid & 15) * 64; }
  else { int r2 = rid - TT * NH; t = r2 >> 3; p = kb + t * 512 + (r2 & 7) * 64; }

  float v = p[lane];
  float part = __shfl_xor(v, 32);
  int f = lane & 31;
  float c = cosb[t * 32 + f], s = sinb[t * 32 + f];
  float o = (lane < 32) ? (v * c - part * s) : (part * s + v * c);
  float ss = o * o;
#pragma unroll
  for (int off = 32; off; off >>= 1) ss += __shfl_xor(ss, off);
  float r = rsqrtf(ss * (1.0f / 64.0f) + EPS_);
  p[lane] = o * r;
}

// ---------------------------------------------------------------------------
// Tropical causal attention (fp32 core), y written as bf16 for out-proj.
// ---------------------------------------------------------------------------
__global__ __launch_bounds__(256) void attn_kernel(
    const float* __restrict__ qb, const float* __restrict__ kb,
    const float* __restrict__ vb, ushort* __restrict__ yb)
{
  __shared__ float kT[64][65];
  __shared__ float vS[64][65];
  __shared__ __align__(16) float qS[4][64];
  __shared__ __align__(16) float pS[4][64];

  const int tid = threadIdx.x;
  const int w = tid >> 6, lane = tid & 63;
  const int h = blockIdx.y, g = h >> 1;
  const int i0 = blockIdx.x * 4;
  const int i = i0 + w;

  qS[w][lane] = qb[i * 1024 + h * 64 + lane];

  float acc = 0.f, l = 0.f, m = -INFINITY;
  const int jt_max = i0 >> 6;

  for (int jt = 0; jt <= jt_max; ++jt) {
    const int j0 = jt * 64;
    __syncthreads();
    {
      int c4 = tid & 15, r0 = tid >> 4;
#pragma unroll
      for (int rr = 0; rr < 4; ++rr) {
        int r = r0 + rr * 16;
        float4 kv = *reinterpret_cast<const float4*>(&kb[(j0 + r) * 512 + g * 64 + c4 * 4]);
        kT[c4 * 4 + 0][r] = kv.x; kT[c4 * 4 + 1][r] = kv.y;
        kT[c4 * 4 + 2][r] = kv.z; kT[c4 * 4 + 3][r] = kv.w;
        float4 vv = *reinterpret_cast<const float4*>(&vb[(j0 + r) * 512 + g * 64 + c4 * 4]);
        vS[r][c4 * 4 + 0] = vv.x; vS[r][c4 * 4 + 1] = vv.y;
        vS[r][c4 * 4 + 2] = vv.z; vS[r][c4 * 4 + 3] = vv.w;
      }
    }
    __syncthreads();

    float s = -INFINITY;
    const float4* q4 = reinterpret_cast<const float4*>(qS[w]);
#pragma unroll
    for (int d4 = 0; d4 < 16; ++d4) {
      float4 qv = q4[d4];
      s = fmaxf(s, qv.x + kT[d4 * 4 + 0][lane]);
      s = fmaxf(s, qv.y + kT[d4 * 4 + 1][lane]);
      s = fmaxf(s, qv.z + kT[d4 * 4 + 2][lane]);
      s = fmaxf(s, qv.w + kT[d4 * 4 + 3][lane]);
    }
    if (j0 + lane > i) s = -INFINITY;

    float mt = s;
#pragma unroll
    for (int off = 32; off; off >>= 1) mt = fmaxf(mt, __shfl_xor(mt, off));
    float mnew = fmaxf(m, mt);
    float scale = __expf(m - mnew);
    float pp = __expf(s - mnew);
    float psum = pp;
#pragma unroll
    for (int off = 32; off; off >>= 1) psum += __shfl_xor(psum, off);
    l = l * scale + psum;
    acc *= scale;
    m = mnew;
    pS[w][lane] = pp;
    __syncthreads();

    const float4* p4 = reinterpret_cast<const float4*>(pS[w]);
#pragma unroll
    for (int j4 = 0; j4 < 16; ++j4) {
      float4 pv = p4[j4];
      acc = fmaf(pv.x, vS[j4 * 4 + 0][lane], acc);
      acc = fmaf(pv.y, vS[j4 * 4 + 1][lane], acc);
      acc = fmaf(pv.z, vS[j4 * 4 + 2][lane], acc);
      acc = fmaf(pv.w, vS[j4 * 4 + 3][lane], acc);
    }
  }

  yb[i * 1024 + h * 64 + lane] = f2bf(acc / l);
}

// ---------------------------------------------------------------------------
extern "C" void kernel_launch(void* const* d_in, const int* in_sizes, int n_in,
                              void* d_out, int out_size, void* d_ws, size_t ws_size,
                              hipStream_t stream) {
  const float* x    = (const float*)d_in[0];
  const float* cosb = (const float*)d_in[1];
  const float* sinb = (const float*)d_in[2];
  const float* Wq   = (const float*)d_in[3];
  const float* Wk   = (const float*)d_in[4];
  const float* Wv   = (const float*)d_in[5];
  const float* Wo   = (const float*)d_in[6];
  float* out = (float*)d_out;

  float* wsf = (float*)d_ws;
  float* qbuf = wsf;                      // 512x1024 f32
  float* kbuf = qbuf + TT * CC;           // 512x512  f32
  float* vbuf = kbuf + TT * 512;          // 512x512  f32
  ushort* wsu = (ushort*)(vbuf + TT * 512);
  ushort* xb  = wsu;                      // 512x1024 bf16
  ushort* yb  = xb + TT * CC;             // 512x1024 bf16
  ushort* Wtq = yb + TT * CC;             // 1024x1024 bf16
  ushort* Wtk = Wtq + CC * CC;            // 512x1024 bf16
  ushort* Wtv = Wtk + 512 * CC;           // 512x1024 bf16
  ushort* Wto = Wtv + 512 * CC;           // 1024x1024 bf16

  prep_kernel<<<dim3(1024), 256, 0, stream>>>(x, Wq, Wk, Wv, Wo, xb, Wtq, Wtk, Wtv, Wto);
  qkv_mfma_kernel<<<dim3(32, 8), 256, 0, stream>>>(xb, Wtq, Wtk, Wtv, qbuf, kbuf, vbuf);
  rope_rms_kernel<<<dim3((TT * NH + TT * NKV) / 4), 256, 0, stream>>>(qbuf, kbuf, cosb, sinb);
  attn_kernel<<<dim3(TT / 4, NH), 256, 0, stream>>>(qbuf, kbuf, vbuf, yb);
  out_mfma_kernel<<<dim3(16, 8), 256, 0, stream>>>(yb, Wto, out);
}

// Round 3
// 78.710 us; speedup vs baseline: 2.5913x; 1.2023x over previous
//
#include <hip/hip_runtime.h>
#include <hip/hip_bf16.h>
#include <math.h>

#define TT 512
#define CC 1024
#define NH 16
#define NKV 8
#define HD 64
static constexpr float EPS_ = 1e-6f;

typedef short bf16x8 __attribute__((ext_vector_type(8)));
typedef float f32x4 __attribute__((ext_vector_type(4)));

__device__ __forceinline__ ushort f2bf(float f) {
  union { __hip_bfloat16 h; ushort u; } cv;
  cv.h = __float2bfloat16(f);
  return cv.u;
}

// ---------------------------------------------------------------------------
// prep: x -> bf16 (same layout); Wq/Wk/Wv/Wo -> transposed bf16 Wt[n][k]
// ---------------------------------------------------------------------------
__global__ __launch_bounds__(256) void prep_kernel(
    const float* __restrict__ x,
    const float* __restrict__ Wq, const float* __restrict__ Wk,
    const float* __restrict__ Wv, const float* __restrict__ Wo,
    ushort* __restrict__ xb, ushort* __restrict__ Wtq, ushort* __restrict__ Wtk,
    ushort* __restrict__ Wtv, ushort* __restrict__ Wto)
{
  int b = blockIdx.x;
  if (b < 256) {
    int base = b * 2048 + threadIdx.x * 8;
    float4 f0 = *reinterpret_cast<const float4*>(&x[base]);
    float4 f1 = *reinterpret_cast<const float4*>(&x[base + 4]);
    union { ushort u[8]; uint4 v; } pk;
    pk.u[0] = f2bf(f0.x); pk.u[1] = f2bf(f0.y); pk.u[2] = f2bf(f0.z); pk.u[3] = f2bf(f0.w);
    pk.u[4] = f2bf(f1.x); pk.u[5] = f2bf(f1.y); pk.u[6] = f2bf(f1.z); pk.u[7] = f2bf(f1.w);
    *reinterpret_cast<uint4*>(&xb[base]) = pk.v;
    return;
  }
  b -= 256;
  const float* W; ushort* Wt; int ldW, tr, tc;
  if (b < 256)      { W = Wq; Wt = Wtq; ldW = 1024; tr = b >> 4;       tc = b & 15; }
  else if (b < 384) { int q = b - 256; W = Wk; Wt = Wtk; ldW = 512; tr = q >> 3; tc = q & 7; }
  else if (b < 512) { int q = b - 384; W = Wv; Wt = Wtv; ldW = 512; tr = q >> 3; tc = q & 7; }
  else              { int q = b - 512; W = Wo; Wt = Wto; ldW = 1024; tr = q >> 4; tc = q & 15; }
  const int k0 = tr * 64, n0 = tc * 64;
  __shared__ float ft[64][65];
  const int t = threadIdx.x;
#pragma unroll
  for (int it = 0; it < 4; ++it) {
    int q = t + it * 256;
    int r = q >> 4, c4 = q & 15;
    float4 f = *reinterpret_cast<const float4*>(&W[(k0 + r) * ldW + n0 + c4 * 4]);
    ft[r][c4 * 4 + 0] = f.x; ft[r][c4 * 4 + 1] = f.y;
    ft[r][c4 * 4 + 2] = f.z; ft[r][c4 * 4 + 3] = f.w;
  }
  __syncthreads();
#pragma unroll
  for (int it = 0; it < 2; ++it) {
    int q = t + it * 256;
    int n = q >> 3, kc = q & 7;
    union { ushort u[8]; uint4 v; } pk;
#pragma unroll
    for (int j = 0; j < 8; ++j) pk.u[j] = f2bf(ft[kc * 8 + j][n]);
    *reinterpret_cast<uint4*>(&Wt[(n0 + n) * 1024 + k0 + kc * 8]) = pk.v;
  }
}

// ---------------------------------------------------------------------------
// bf16 MFMA GEMM: C[64x64 tile] = A[M][1024] @ Bt[N][1024]^T, fp32 out.
// ---------------------------------------------------------------------------
__device__ __forceinline__ void mfma_gemm64(
    const ushort* __restrict__ A, const ushort* __restrict__ Bt,
    float* __restrict__ C, int ldC, int row0, int col0)
{
  __shared__ ushort At[64][72];
  __shared__ ushort Bs[64][72];
  const int tid = threadIdx.x;
  const int lane = tid & 63, w = tid >> 6;
  const int m0 = (w & 1) * 32, n0 = (w >> 1) * 32;
  const int lr = lane & 15, lk = (lane >> 4) * 8;
  f32x4 acc[2][2] = {};
  const int sr = tid >> 2;
  const int sc = (tid & 3) * 16;
  const ushort* Ap = &A[(row0 + sr) * 1024 + sc];
  const ushort* Bp = &Bt[(col0 + sr) * 1024 + sc];

  for (int k0 = 0; k0 < 1024; k0 += 64) {
    __syncthreads();
    uint4 a0 = *reinterpret_cast<const uint4*>(Ap + k0);
    uint4 a1 = *reinterpret_cast<const uint4*>(Ap + k0 + 8);
    uint4 b0 = *reinterpret_cast<const uint4*>(Bp + k0);
    uint4 b1 = *reinterpret_cast<const uint4*>(Bp + k0 + 8);
    *reinterpret_cast<uint4*>(&At[sr][sc]) = a0;
    *reinterpret_cast<uint4*>(&At[sr][sc + 8]) = a1;
    *reinterpret_cast<uint4*>(&Bs[sr][sc]) = b0;
    *reinterpret_cast<uint4*>(&Bs[sr][sc + 8]) = b1;
    __syncthreads();
#pragma unroll
    for (int kk = 0; kk < 2; ++kk) {
      bf16x8 af[2], bg[2];
      af[0] = *reinterpret_cast<const bf16x8*>(&At[m0 + lr][kk * 32 + lk]);
      af[1] = *reinterpret_cast<const bf16x8*>(&At[m0 + 16 + lr][kk * 32 + lk]);
      bg[0] = *reinterpret_cast<const bf16x8*>(&Bs[n0 + lr][kk * 32 + lk]);
      bg[1] = *reinterpret_cast<const bf16x8*>(&Bs[n0 + 16 + lr][kk * 32 + lk]);
#pragma unroll
      for (int mi = 0; mi < 2; ++mi)
#pragma unroll
        for (int ni = 0; ni < 2; ++ni)
          acc[mi][ni] = __builtin_amdgcn_mfma_f32_16x16x32_bf16(af[mi], bg[ni], acc[mi][ni], 0, 0, 0);
    }
  }
  const int crow = (lane >> 4) * 4, ccol = lane & 15;
#pragma unroll
  for (int mi = 0; mi < 2; ++mi)
#pragma unroll
    for (int ni = 0; ni < 2; ++ni) {
      int rb = row0 + m0 + mi * 16 + crow;
      int cc = col0 + n0 + ni * 16 + ccol;
#pragma unroll
      for (int r = 0; r < 4; ++r)
        C[(rb + r) * ldC + cc] = acc[mi][ni][r];
    }
}

__global__ __launch_bounds__(256) void qkv_mfma_kernel(
    const ushort* __restrict__ xb,
    const ushort* __restrict__ Wtq, const ushort* __restrict__ Wtk, const ushort* __restrict__ Wtv,
    float* __restrict__ qb, float* __restrict__ kb, float* __restrict__ vb)
{
  int bx = blockIdx.x, by = blockIdx.y;
  if (bx < 16)      mfma_gemm64(xb, Wtq, qb, 1024, by * 64, bx * 64);
  else if (bx < 24) mfma_gemm64(xb, Wtk, kb, 512, by * 64, (bx - 16) * 64);
  else              mfma_gemm64(xb, Wtv, vb, 512, by * 64, (bx - 24) * 64);
}

__global__ __launch_bounds__(256) void out_mfma_kernel(
    const ushort* __restrict__ yb, const ushort* __restrict__ Wto, float* __restrict__ out)
{
  mfma_gemm64(yb, Wto, out, 1024, blockIdx.y * 64, blockIdx.x * 64);
}

// ---------------------------------------------------------------------------
// RoPE + RMS-norm, in place (fp32).
// ---------------------------------------------------------------------------
__global__ __launch_bounds__(256) void rope_rms_kernel(
    float* __restrict__ qb, float* __restrict__ kb,
    const float* __restrict__ cosb, const float* __restrict__ sinb)
{
  int rid = blockIdx.x * 4 + (threadIdx.x >> 6);
  int lane = threadIdx.x & 63;
  float* p; int t;
  if (rid < TT * NH) { t = rid >> 4; p = qb + t * 1024 + (rid & 15) * 64; }
  else { int r2 = rid - TT * NH; t = r2 >> 3; p = kb + t * 512 + (r2 & 7) * 64; }

  float v = p[lane];
  float part = __shfl_xor(v, 32);
  int f = lane & 31;
  float c = cosb[t * 32 + f], s = sinb[t * 32 + f];
  float o = (lane < 32) ? (v * c - part * s) : (part * s + v * c);
  float ss = o * o;
#pragma unroll
  for (int off = 32; off; off >>= 1) ss += __shfl_xor(ss, off);
  float r = rsqrtf(ss * (1.0f / 64.0f) + EPS_);
  p[lane] = o * r;
}

// ---------------------------------------------------------------------------
// Tropical causal attention, v2.
// Block = (head, 16 q-rows). 256 thr = 4 waves, 4 q-rows per wave.
// Per 64-j tile: K,V staged in LDS once; each wave holds K-row (lane=j) and
// V-column (lane=d) in registers; score and PV loops are register-resident
// VALU with only broadcast LDS reads. Heavy chunks scheduled first.
// ---------------------------------------------------------------------------
__global__ __launch_bounds__(256) void attn_kernel(
    const float* __restrict__ qb, const float* __restrict__ kb,
    const float* __restrict__ vb, ushort* __restrict__ yb)
{
  __shared__ float kS[64][76];
  __shared__ float vS[64][76];
  __shared__ __align__(16) float qS[16][64];
  __shared__ __align__(16) float pS[4][4][64];

  const int tid = threadIdx.x;
  const int w = tid >> 6, lane = tid & 63;
  const int bx = blockIdx.x;
  const int h = bx & 15;
  const int qt = 31 - (bx >> 4);      // heavy chunks first
  const int g = h >> 1;
  const int i0 = qt * 16;
  const int nt = i0 / 64 + 1;

  // stage the 16 q rows
  {
    int r = tid >> 4, c4 = tid & 15;
    float4 qv = *reinterpret_cast<const float4*>(&qb[(i0 + r) * 1024 + h * 64 + c4 * 4]);
    *reinterpret_cast<float4*>(&qS[r][c4 * 4]) = qv;
  }

  float acc[4] = {0.f, 0.f, 0.f, 0.f};
  float l[4]   = {0.f, 0.f, 0.f, 0.f};
  float m[4]   = {-INFINITY, -INFINITY, -INFINITY, -INFINITY};

  for (int jt = 0; jt < nt; ++jt) {
    const int j0 = jt * 64;
    __syncthreads();
    // stage K,V tiles (row-major, coalesced)
#pragma unroll
    for (int it = 0; it < 4; ++it) {
      int s = tid + it * 256;
      int r = s >> 4, c4 = s & 15;
      *reinterpret_cast<float4*>(&kS[r][c4 * 4]) =
          *reinterpret_cast<const float4*>(&kb[(j0 + r) * 512 + g * 64 + c4 * 4]);
      *reinterpret_cast<float4*>(&vS[r][c4 * 4]) =
          *reinterpret_cast<const float4*>(&vb[(j0 + r) * 512 + g * 64 + c4 * 4]);
    }
    __syncthreads();

    // K row (j = j0+lane) into registers
    float kreg[64];
#pragma unroll
    for (int d4 = 0; d4 < 16; ++d4)
      *reinterpret_cast<float4*>(&kreg[d4 * 4]) =
          *reinterpret_cast<const float4*>(&kS[lane][d4 * 4]);
    // V column (d = lane) into registers
    float vreg[64];
#pragma unroll
    for (int j = 0; j < 64; ++j) vreg[j] = vS[j][lane];

    const bool lastT = (jt == nt - 1);

#pragma unroll
    for (int q = 0; q < 4; ++q) {
      const int i = i0 + 4 * w + q;
      const float4* q4 = reinterpret_cast<const float4*>(qS[4 * w + q]);
      float s0 = -INFINITY, s1 = -INFINITY;
#pragma unroll
      for (int d4 = 0; d4 < 16; ++d4) {
        float4 qv = q4[d4];
        s0 = fmaxf(fmaxf(s0, qv.x + kreg[d4 * 4 + 0]), qv.y + kreg[d4 * 4 + 1]);
        s1 = fmaxf(fmaxf(s1, qv.z + kreg[d4 * 4 + 2]), qv.w + kreg[d4 * 4 + 3]);
      }
      float s = fmaxf(s0, s1);
      if (lastT && (j0 + lane > i)) s = -INFINITY;

      float mt = s;
#pragma unroll
      for (int off = 32; off; off >>= 1) mt = fmaxf(mt, __shfl_xor(mt, off));
      float mnew = fmaxf(m[q], mt);
      float scale = __expf(m[q] - mnew);
      float pp = __expf(s - mnew);
      float ps = pp;
#pragma unroll
      for (int off = 32; off; off >>= 1) ps += __shfl_xor(ps, off);
      l[q] = l[q] * scale + ps;
      acc[q] *= scale;
      m[q] = mnew;
      pS[w][q][lane] = pp;
    }

    // PV: register-resident V, broadcast P reads
#pragma unroll
    for (int q = 0; q < 4; ++q) {
      const float4* p4 = reinterpret_cast<const float4*>(pS[w][q]);
      float a = acc[q];
#pragma unroll
      for (int j4 = 0; j4 < 16; ++j4) {
        float4 pv = p4[j4];
        a = fmaf(pv.x, vreg[j4 * 4 + 0], a);
        a = fmaf(pv.y, vreg[j4 * 4 + 1], a);
        a = fmaf(pv.z, vreg[j4 * 4 + 2], a);
        a = fmaf(pv.w, vreg[j4 * 4 + 3], a);
      }
      acc[q] = a;
    }
  }

#pragma unroll
  for (int q = 0; q < 4; ++q) {
    int i = i0 + 4 * w + q;
    yb[i * 1024 + h * 64 + lane] = f2bf(acc[q] / l[q]);
  }
}

// ---------------------------------------------------------------------------
extern "C" void kernel_launch(void* const* d_in, const int* in_sizes, int n_in,
                              void* d_out, int out_size, void* d_ws, size_t ws_size,
                              hipStream_t stream) {
  const float* x    = (const float*)d_in[0];
  const float* cosb = (const float*)d_in[1];
  const float* sinb = (const float*)d_in[2];
  const float* Wq   = (const float*)d_in[3];
  const float* Wk   = (const float*)d_in[4];
  const float* Wv   = (const float*)d_in[5];
  const float* Wo   = (const float*)d_in[6];
  float* out = (float*)d_out;

  float* wsf = (float*)d_ws;
  float* qbuf = wsf;                      // 512x1024 f32
  float* kbuf = qbuf + TT * CC;           // 512x512  f32
  float* vbuf = kbuf + TT * 512;          // 512x512  f32
  ushort* wsu = (ushort*)(vbuf + TT * 512);
  ushort* xb  = wsu;                      // 512x1024 bf16
  ushort* yb  = xb + TT * CC;             // 512x1024 bf16
  ushort* Wtq = yb + TT * CC;             // 1024x1024 bf16
  ushort* Wtk = Wtq + CC * CC;            // 512x1024 bf16
  ushort* Wtv = Wtk + 512 * CC;           // 512x1024 bf16
  ushort* Wto = Wtv + 512 * CC;           // 1024x1024 bf16

  prep_kernel<<<dim3(1024), 256, 0, stream>>>(x, Wq, Wk, Wv, Wo, xb, Wtq, Wtk, Wtv, Wto);
  qkv_mfma_kernel<<<dim3(32, 8), 256, 0, stream>>>(xb, Wtq, Wtk, Wtv, qbuf, kbuf, vbuf);
  rope_rms_kernel<<<dim3((TT * NH + TT * NKV) / 4), 256, 0, stream>>>(qbuf, kbuf, cosb, sinb);
  attn_kernel<<<dim3(512), 256, 0, stream>>>(qbuf, kbuf, vbuf, yb);
  out_mfma_kernel<<<dim3(16, 8), 256, 0, stream>>>(yb, Wto, out);
}